// Round 1
// baseline (26.555 us; speedup 1.0000x reference)
//
#include <hip/hip_runtime.h>
#include <math.h>

#define N_ 16
#define P_ 2048
#define K_ 512
#define H_ 256
#define W_ 256
#define ZTHRESH_ 2.0f

// ---------------------------------------------------------------------------
// K1: gather uv at all pts (uvp), and compute line-intersection Y per (n,k).
//   items [0, N*P)          -> uvp gather
//   items [N*P, N*P + N*K)  -> Y solve
// ---------------------------------------------------------------------------
__global__ __launch_bounds__(256) void k1_gather(
    const float* __restrict__ uv_img, const int* __restrict__ pts,
    const int* __restrict__ pair, float* __restrict__ Y,
    float* __restrict__ uvp) {
  int id = blockIdx.x * 256 + threadIdx.x;
  if (id < N_ * P_) {
    int n = id / P_, p = id % P_;
    int c0 = pts[(n * P_ + p) * 2 + 0];
    int c1 = pts[(n * P_ + p) * 2 + 1];
    const float* base = uv_img + (size_t)n * 2 * H_ * W_;
    uvp[(n * P_ + p) * 2 + 0] = base[c0 * W_ + c1];
    uvp[(n * P_ + p) * 2 + 1] = base[H_ * W_ + c0 * W_ + c1];
  } else {
    int j = id - N_ * P_;
    if (j < N_ * K_) {
      int n = j / K_, k = j % K_;
      int i0 = pair[(n * K_ + k) * 2 + 0];
      int i1 = pair[(n * K_ + k) * 2 + 1];
      int p0y = pts[(n * P_ + i0) * 2 + 0], p0x = pts[(n * P_ + i0) * 2 + 1];
      int p1y = pts[(n * P_ + i1) * 2 + 0], p1x = pts[(n * P_ + i1) * 2 + 1];
      const float* base = uv_img + (size_t)n * 2 * H_ * W_;
      float u00 = base[p0y * W_ + p0x];            // uv0 ch0
      float u01 = base[H_ * W_ + p0y * W_ + p0x];  // uv0 ch1
      float u10 = base[p1y * W_ + p1x];            // uv1 ch0
      float u11 = base[H_ * W_ + p1y * W_ + p1x];  // uv1 ch1
      float B0 = (float)(p1y - p0y);
      float B1 = (float)(p1x - p0x);
      // A = [[u00, -u10], [u01, -u11]], X = A^-1 B (Cramer). pinv==inv a.e.
      float det = u10 * u01 - u00 * u11;
      float x0 = (u10 * B1 - B0 * u11) / det;
      Y[(n * K_ + k) * 2 + 0] = x0 * u00 + (float)p0y;
      Y[(n * K_ + k) * 2 + 1] = x0 * u01 + (float)p0x;
    }
  }
}

// ---------------------------------------------------------------------------
// K2: per-n mean/std (ddof=1) over K, bad flags; also zero vote counters.
// 16 blocks x 512 threads (one thread per k).
// ---------------------------------------------------------------------------
__global__ __launch_bounds__(512) void k2_stats(
    const float* __restrict__ Y, int* __restrict__ bad,
    int* __restrict__ wcnt, int* __restrict__ hcnt) {
  int n = blockIdx.x;
  int tid = threadIdx.x;
  float y0 = Y[(n * K_ + tid) * 2 + 0];
  float y1 = Y[(n * K_ + tid) * 2 + 1];
  wcnt[n * K_ + tid] = 0;
  hcnt[n * K_ + tid] = 0;

  __shared__ float lds[8][2];
  __shared__ float mean0s, mean1s, std0s, std1s;
  int wave = tid >> 6, lane = tid & 63;

  // pass 1: mean (NaN propagates, matching jnp semantics)
  float a0 = y0, a1 = y1;
  for (int off = 32; off >= 1; off >>= 1) {
    a0 += __shfl_down(a0, off);
    a1 += __shfl_down(a1, off);
  }
  if (lane == 0) { lds[wave][0] = a0; lds[wave][1] = a1; }
  __syncthreads();
  if (tid == 0) {
    float t0 = 0.f, t1 = 0.f;
    for (int i = 0; i < 8; i++) { t0 += lds[i][0]; t1 += lds[i][1]; }
    mean0s = t0 / (float)K_;
    mean1s = t1 / (float)K_;
  }
  __syncthreads();
  float m0 = mean0s, m1 = mean1s;
  float e0 = y0 - m0, e1 = y1 - m1;

  // pass 2: variance (ddof=1)
  a0 = e0 * e0; a1 = e1 * e1;
  for (int off = 32; off >= 1; off >>= 1) {
    a0 += __shfl_down(a0, off);
    a1 += __shfl_down(a1, off);
  }
  __syncthreads();
  if (lane == 0) { lds[wave][0] = a0; lds[wave][1] = a1; }
  __syncthreads();
  if (tid == 0) {
    float t0 = 0.f, t1 = 0.f;
    for (int i = 0; i < 8; i++) { t0 += lds[i][0]; t1 += lds[i][1]; }
    std0s = sqrtf(t0 / (float)(K_ - 1));
    std1s = sqrtf(t1 / (float)(K_ - 1));
  }
  __syncthreads();
  float z0 = fabsf(e0 / std0s), z1 = fabsf(e1 / std1s);
  int b = (z0 > ZTHRESH_) | (z1 > ZTHRESH_) | (y0 != y0) | (y1 != y1);
  bad[n * K_ + tid] = b;
}

// ---------------------------------------------------------------------------
// K3: vote counting. grid = 16 n x 2 ktiles x 8 ptiles = 256 blocks x 256 thr.
// Each thread owns one k; ptile of 256 points staged in LDS (broadcast reads).
// sign(dot(d/||d||, uv)) == sign(dot(d, uv)) incl. d==0 / NaN cases.
// ---------------------------------------------------------------------------
__global__ __launch_bounds__(256) void k3_votes(
    const float* __restrict__ Y, const int* __restrict__ pts,
    const float* __restrict__ uvp, int* __restrict__ wcnt,
    int* __restrict__ hcnt) {
  int b = blockIdx.x;
  int n = b >> 4;
  int kt = (b >> 3) & 1;
  int pt = b & 7;
  int tid = threadIdx.x;

  __shared__ float4 sf[256];  // {pty_f, ptx_f, u, v}
  __shared__ int2 si[256];    // {pty, ptx}

  int p = pt * 256 + tid;
  int py = pts[(n * P_ + p) * 2 + 0];
  int px = pts[(n * P_ + p) * 2 + 1];
  float u = uvp[(n * P_ + p) * 2 + 0];
  float v = uvp[(n * P_ + p) * 2 + 1];
  sf[tid] = make_float4((float)py, (float)px, u, v);
  si[tid] = make_int2(py, px);
  __syncthreads();

  int k = kt * 256 + tid;
  float y0 = Y[(n * K_ + k) * 2 + 0];
  float y1 = Y[(n * K_ + k) * 2 + 1];
  int iy0 = (int)y0, iy1 = (int)y1;
  int cnt = 0, hm = 0;
#pragma unroll 4
  for (int i = 0; i < 256; i++) {
    float4 f = sf[i];
    int2 ii = si[i];
    float d0 = y0 - f.x;
    float d1 = y1 - f.y;
    float dot = d0 * f.z + d1 * f.w;
    cnt += (dot > 0.f) ? 1 : 0;
    hm += ((iy0 == ii.x) & (iy1 == ii.y)) ? 1 : 0;
  }
  atomicAdd(&wcnt[n * K_ + k], cnt);
  atomicAdd(&hcnt[n * K_ + k], hm);
}

// ---------------------------------------------------------------------------
// K4: weights + weighted mean -> out (reversed coords). 16 blocks x 512 thr.
// ---------------------------------------------------------------------------
__global__ __launch_bounds__(512) void k4_out(
    const float* __restrict__ Y, const int* __restrict__ bad,
    const int* __restrict__ wcnt, const int* __restrict__ hcnt,
    float* __restrict__ out) {
  int n = blockIdx.x;
  int tid = threadIdx.x;
  float y0 = Y[(n * K_ + tid) * 2 + 0];
  float y1 = Y[(n * K_ + tid) * 2 + 1];
  int bd = bad[n * K_ + tid];
  float w = (float)wcnt[n * K_ + tid];
  if (hcnt[n * K_ + tid] == 1) w *= 5.0f;  // MULT
  if (bd) w = 0.f;
  float yz0 = bd ? 0.f : y0;
  float yz1 = bd ? 0.f : y1;
  float sw = w, s0 = w * yz0, s1 = w * yz1;

  int wave = tid >> 6, lane = tid & 63;
  __shared__ float lds[8][3];
  for (int off = 32; off >= 1; off >>= 1) {
    sw += __shfl_down(sw, off);
    s0 += __shfl_down(s0, off);
    s1 += __shfl_down(s1, off);
  }
  if (lane == 0) { lds[wave][0] = sw; lds[wave][1] = s0; lds[wave][2] = s1; }
  __syncthreads();
  if (tid == 0) {
    float tw = 0.f, t0 = 0.f, t1 = 0.f;
    for (int i = 0; i < 8; i++) {
      tw += lds[i][0]; t0 += lds[i][1]; t1 += lds[i][2];
    }
    float denom = fmaxf(tw, 1.0f);
    out[n * 2 + 0] = t1 / denom;  // pixel_xy reverses the coord order
    out[n * 2 + 1] = t0 / denom;
  }
}

extern "C" void kernel_launch(void* const* d_in, const int* in_sizes, int n_in,
                              void* d_out, int out_size, void* d_ws,
                              size_t ws_size, hipStream_t stream) {
  const float* uv_img = (const float*)d_in[0];
  const int* pts = (const int*)d_in[1];
  const int* pair = (const int*)d_in[2];
  float* out = (float*)d_out;

  float* Y = (float*)d_ws;                  // N*K*2
  float* uvp = Y + N_ * K_ * 2;             // N*P*2
  int* bad = (int*)(uvp + N_ * P_ * 2);     // N*K
  int* wcnt = bad + N_ * K_;                // N*K
  int* hcnt = wcnt + N_ * K_;               // N*K

  hipLaunchKernelGGL(k1_gather, dim3((N_ * P_ + N_ * K_) / 256), dim3(256), 0,
                     stream, uv_img, pts, pair, Y, uvp);
  hipLaunchKernelGGL(k2_stats, dim3(N_), dim3(K_), 0, stream, Y, bad, wcnt,
                     hcnt);
  hipLaunchKernelGGL(k3_votes, dim3(256), dim3(256), 0, stream, Y, pts, uvp,
                     wcnt, hcnt);
  hipLaunchKernelGGL(k4_out, dim3(N_), dim3(K_), 0, stream, Y, bad, wcnt, hcnt,
                     out);
}